// Round 5
// baseline (256.815 us; speedup 1.0000x reference)
//
#include <hip/hip_runtime.h>
#include <hip/hip_bf16.h>
#include <stdint.h>

#define NNODES 100000
#define NEDGES 1000000
#define DIM 64
#define NRELS 16
#define EPB 2048
#define NB ((NEDGES + EPB - 1) / EPB)   /* 489 */
#define PADCAP (NEDGES + NRELS * 64)    /* 1001024 */
#define MAXTILES (PADCAP / 64)          /* 15641 */
#define NDN NNODES
#define DCH 1024
#define NCHUNK ((NDN + DCH - 1) / DCH)  /* 98 */

// setup grid split
#define FEAT_BLKS 6250
#define W_BLKS 256
#define SETUP_BLKS (FEAT_BLKS + W_BLKS + NB)

// ws layout (bytes):
//   featB  @ 0          : ushort[NNODES*64]   -> 12,800,000
//   Wt     @ 12800000   : ushort[16*64*64]    -> 12,931,072
//   hist   @ 12931072   : int[NB*16]          -> 12,963,840
//   bbase  @ 12963840   : int[NB*16]          -> 12,996,608
//   Pve    @ 12996608   : int[33]             -> 12,996,864
//   dhist  @ 12996864   : int[NDN]            -> 13,396,992
//   dbase  @ 13396992   : int[NDN]            -> 13,797,120  (EXCLUSIVE starts, immutable)
//   csum   @ 13797120   : int[NCHUNK]         -> 13,797,632
//   rank   @ 13797632   : ushort[NEDGES]      -> 15,797,632  (within-dst-segment rank)
//   pairS  @ 15797632   : int2[PADCAP]        -> 23,805,824  {src, dstpos|dst}
//   msgE   @ 23805824   : ushort[NEDGES*64]   -> 151,805,824
#define WS_NEED 151805824ull

using short8  = __attribute__((ext_vector_type(8))) short;
using floatx4 = __attribute__((ext_vector_type(4))) float;
using uintx4  = __attribute__((ext_vector_type(4))) unsigned int;

__device__ __forceinline__ unsigned short f2bf(float f) {
    union { float f; uint32_t u; } v; v.f = f;
    uint32_t u = v.u;
    return (unsigned short)((u + 0x7FFFu + ((u >> 16) & 1u)) >> 16);
}
__device__ __forceinline__ float bf2f(uint32_t u16) {
    union { uint32_t u; float f; } v; v.u = u16 << 16;
    return v.f;
}
__device__ __forceinline__ uint32_t pk2(float a, float b) {
    __hip_bfloat162 h = __float22bfloat162_rn(make_float2(a, b));
    union { __hip_bfloat162 h; uint32_t u; } v; v.h = h;
    return v.u;
}

// fused setup: feat->bf16, W->bf16 transposed, relation hist + dst hist/rank
__global__ void k_setup(const float* __restrict__ feat, const float* __restrict__ W,
                        const int* __restrict__ et, const int* __restrict__ dst,
                        unsigned short* __restrict__ featB, unsigned short* __restrict__ Wt,
                        int* __restrict__ hist, int* __restrict__ dhist,
                        unsigned short* __restrict__ rank) {
    __shared__ int cnt[16];
    const int b = blockIdx.x;
    if (b < FEAT_BLKS) {
        int i = (b * 256 + threadIdx.x) * 4;
        const float4 f = *(const float4*)(feat + i);
        ushort4 o;
        o.x = f2bf(f.x); o.y = f2bf(f.y); o.z = f2bf(f.z); o.w = f2bf(f.w);
        *(ushort4*)(featB + i) = o;
    } else if (b < FEAT_BLKS + W_BLKS) {
        int t = (b - FEAT_BLKS) * 256 + threadIdx.x;   // 65536 total
        int r = t >> 12, n = (t >> 6) & 63, k = t & 63;
        Wt[t] = f2bf(W[(r << 12) + (k << 6) + n]);     // Wt[r][n][k] = W[r][k][n]
    } else {
        const int bb = b - (FEAT_BLKS + W_BLKS);
        if (threadIdx.x < 16) cnt[threadIdx.x] = 0;
        __syncthreads();
        int start = bb * EPB;
        int end = min(NEDGES, start + EPB);
        for (int i = start + threadIdx.x; i < end; i += 256) {
            atomicAdd(&cnt[et[i]], 1);
            rank[i] = (unsigned short)atomicAdd(&dhist[dst[i]], 1);
        }
        __syncthreads();
        if (threadIdx.x < 16) hist[bb * 16 + threadIdx.x] = cnt[threadIdx.x];
    }
}

__global__ void k_scan(const int* __restrict__ hist, int* __restrict__ bbase,
                       int* __restrict__ Pve) {
    __shared__ int s_cnt[16];
    __shared__ int s_P[17];
    int w = threadIdx.x >> 6;
    int lane = threadIdx.x & 63;
    int carry = 0;
    for (int c = 0; c < NB; c += 64) {
        int idx = c + lane;
        int v = (idx < NB) ? hist[idx * 16 + w] : 0;
        int x = v;
        #pragma unroll
        for (int off = 1; off < 64; off <<= 1) {
            int y = __shfl_up(x, off);
            if (lane >= off) x += y;
        }
        if (idx < NB) bbase[idx * 16 + w] = carry + x - v;
        carry += __shfl(x, 63);
    }
    if (lane == 0) s_cnt[w] = carry;
    __syncthreads();
    if (threadIdx.x == 0) {
        int p = 0;
        for (int r = 0; r < 16; ++r) {
            s_P[r] = p;
            Pve[r] = p;
            Pve[17 + r] = p + s_cnt[r];
            p += (s_cnt[r] + 63) & ~63;
        }
        s_P[16] = p;
        Pve[16] = p;
    }
    __syncthreads();
    int pw = s_P[w];
    for (int idx = lane; idx < NB; idx += 64)
        bbase[idx * 16 + w] += pw;
}

// per-chunk exclusive scan (1024/block) + chunk totals
__global__ void k_dscanA(const int* __restrict__ dhist, int* __restrict__ dbase,
                         int* __restrict__ csum) {
    __shared__ int wsum[16];
    __shared__ int woff[16];
    int t = threadIdx.x;
    int i = blockIdx.x * DCH + t;
    int v = (i < NDN) ? dhist[i] : 0;
    int lane = t & 63, wv = t >> 6;
    int x = v;
    #pragma unroll
    for (int off = 1; off < 64; off <<= 1) {
        int y = __shfl_up(x, off);
        if (lane >= off) x += y;
    }
    if (lane == 63) wsum[wv] = x;
    __syncthreads();
    if (wv == 0) {
        int s = (lane < 16) ? wsum[lane] : 0;
        #pragma unroll
        for (int off = 1; off < 16; off <<= 1) {
            int y = __shfl_up(s, off);
            if (lane >= off) s += y;
        }
        if (lane < 16) woff[lane] = s - wsum[lane];
        if (lane == 15) csum[blockIdx.x] = s;
    }
    __syncthreads();
    if (i < NDN) dbase[i] = woff[wv] + x - v;
}

__global__ void k_dscanB(int* __restrict__ dbase, const int* __restrict__ csum) {
    __shared__ int soff;
    int b = blockIdx.x, t = threadIdx.x;
    if (t < 64) {
        int s = ((t < b) ? csum[t] : 0) + ((t + 64 < b) ? csum[t + 64] : 0);
        #pragma unroll
        for (int off = 32; off >= 1; off >>= 1) s += __shfl_down(s, off);
        if (t == 0) soff = s;
    }
    __syncthreads();
    int i = b * DCH + t;
    if (i < NDN) dbase[i] += soff;
}

// pairS[pos] = {src, dstpos} (phases) or {src, dst} (fallback).
__global__ void k_scatter(const int* __restrict__ et, const int* __restrict__ src,
                          const int* __restrict__ dst, const int* __restrict__ bbase,
                          const int* __restrict__ dbase,
                          const unsigned short* __restrict__ rank,
                          int2* __restrict__ pairS, int buildPos) {
    __shared__ int base[16];
    if (threadIdx.x < 16) base[threadIdx.x] = bbase[blockIdx.x * 16 + threadIdx.x];
    __syncthreads();
    int start = blockIdx.x * EPB;
    int end = min(NEDGES, start + EPB);
    for (int i = start + threadIdx.x; i < end; i += 256) {
        int r = et[i];
        int pos = atomicAdd(&base[r], 1);
        int d = dst[i];
        int second = buildPos ? (dbase[d] + (int)rank[i]) : d;
        pairS[pos] = make_int2(src[i], second);
    }
}

// Phase A: per 64-edge tile (single relation), GEMM -> bf16 msg row at dstpos (NT stores)
__global__ void __launch_bounds__(256)
k_computeA(const unsigned short* __restrict__ featB,
           const unsigned short* __restrict__ Wt,
           const int2* __restrict__ pairS, const int* __restrict__ Pve,
           unsigned short* __restrict__ msgE) {
    __shared__ float lds[4][16 * 68];   // per-wave 16x64 transpose, stride 68
    const int w = threadIdx.x >> 6;
    const int t = blockIdx.x * 4 + w;
    const int base = t * 64;
    const int total = Pve[16];
    if (base >= total) return;
    int r = 0;
    while (base >= Pve[r + 1]) ++r;
    const int validEnd = Pve[17 + r];
    const int lane = threadIdx.x & 63;
    const int quad = lane >> 4;
    const int l16 = lane & 15;

    const unsigned short* wr = Wt + (r << 12);
    short8 bfr[4][2];
    #pragma unroll
    for (int tn = 0; tn < 4; ++tn)
        #pragma unroll
        for (int ks = 0; ks < 2; ++ks)
            bfr[tn][ks] = *(const short8*)(wr + ((tn * 16 + l16) << 6) + ks * 32 + quad * 8);

    const int rr = lane >> 2, seg = lane & 3;
    #pragma unroll
    for (int tm = 0; tm < 4; ++tm) {
        int row = base + tm * 16 + l16;
        int s = (row < validEnd) ? pairS[row].x : 0;
        const unsigned short* fp = featB + (s << 6) + quad * 8;
        short8 a0 = *(const short8*)(fp);
        short8 a1 = *(const short8*)(fp + 32);
        #pragma unroll
        for (int tn = 0; tn < 4; ++tn) {
            floatx4 c = {0.f, 0.f, 0.f, 0.f};
            c = __builtin_amdgcn_mfma_f32_16x16x32_bf16(a0, bfr[tn][0], c, 0, 0, 0);
            c = __builtin_amdgcn_mfma_f32_16x16x32_bf16(a1, bfr[tn][1], c, 0, 0, 0);
            #pragma unroll
            for (int j = 0; j < 4; ++j)
                lds[w][(quad * 4 + j) * 68 + tn * 16 + l16] = c[j];
        }
        // lane l handles output row (l>>2), 16-col segment (l&3)
        int rowi = base + tm * 16 + rr;
        int p = (rowi < validEnd) ? pairS[rowi].y : -1;
        if (p >= 0) {
            const float* lp = &lds[w][rr * 68 + seg * 16];
            uintx4 o0, o1;
            o0.x = pk2(lp[0],  lp[1]);  o0.y = pk2(lp[2],  lp[3]);
            o0.z = pk2(lp[4],  lp[5]);  o0.w = pk2(lp[6],  lp[7]);
            o1.x = pk2(lp[8],  lp[9]);  o1.y = pk2(lp[10], lp[11]);
            o1.z = pk2(lp[12], lp[13]); o1.w = pk2(lp[14], lp[15]);
            uintx4* op = (uintx4*)(msgE + (size_t)p * 64 + seg * 16);
            __builtin_nontemporal_store(o0, op);
            __builtin_nontemporal_store(o1, op + 1);
        }
    }
}

// Phase B: one wave per dst node; msgE segments contiguous (dst-sorted).
// 8 rows/iter: lane reads uintx4 (8 cols, NT) of row start+(lane>>3).
__global__ void __launch_bounds__(256)
k_reduce(const unsigned short* __restrict__ msgE,
         const int* __restrict__ dbase, float* __restrict__ out) {
    int n = blockIdx.x * 4 + (threadIdx.x >> 6);
    if (n >= NDN) return;
    int lane = threadIdx.x & 63;
    int start = dbase[n];
    int end = (n + 1 < NDN) ? dbase[n + 1] : NEDGES;
    int c8 = (lane & 7) * 8;   // ushort col offset
    float a0 = 0.f, a1 = 0.f, a2 = 0.f, a3 = 0.f;
    float a4 = 0.f, a5 = 0.f, a6 = 0.f, a7 = 0.f;
    for (int row = start + (lane >> 3); row < end; row += 8) {
        const uintx4* p = (const uintx4*)(msgE + (size_t)row * 64 + c8);
        uintx4 v = __builtin_nontemporal_load(p);
        a0 += bf2f(v.x & 0xffffu); a1 += bf2f(v.x >> 16);
        a2 += bf2f(v.y & 0xffffu); a3 += bf2f(v.y >> 16);
        a4 += bf2f(v.z & 0xffffu); a5 += bf2f(v.z >> 16);
        a6 += bf2f(v.w & 0xffffu); a7 += bf2f(v.w >> 16);
    }
    #pragma unroll
    for (int m = 8; m <= 32; m <<= 1) {
        a0 += __shfl_xor(a0, m); a1 += __shfl_xor(a1, m);
        a2 += __shfl_xor(a2, m); a3 += __shfl_xor(a3, m);
        a4 += __shfl_xor(a4, m); a5 += __shfl_xor(a5, m);
        a6 += __shfl_xor(a6, m); a7 += __shfl_xor(a7, m);
    }
    if (lane < 8) {
        float* op = out + (size_t)n * 64 + lane * 8;
        *(float4*)(op)     = make_float4(a0, a1, a2, a3);
        *(float4*)(op + 4) = make_float4(a4, a5, a6, a7);
    }
}

// Fallback: atomic epilogue (proven R1 path), pairS = {src, dst}
__global__ void __launch_bounds__(256)
k_compute(const unsigned short* __restrict__ featB,
          const unsigned short* __restrict__ Wt,
          const int2* __restrict__ pairS, const int* __restrict__ Pve,
          float* __restrict__ out) {
    const int t = blockIdx.x * 4 + (threadIdx.x >> 6);
    const int base = t * 64;
    const int total = Pve[16];
    if (base >= total) return;
    int r = 0;
    while (base >= Pve[r + 1]) ++r;
    const int validEnd = Pve[17 + r];
    const int lane = threadIdx.x & 63;
    const int quad = lane >> 4;
    const int l16 = lane & 15;

    const unsigned short* wr = Wt + (r << 12);
    short8 bfr[4][2];
    #pragma unroll
    for (int tn = 0; tn < 4; ++tn)
        #pragma unroll
        for (int ks = 0; ks < 2; ++ks)
            bfr[tn][ks] = *(const short8*)(wr + ((tn * 16 + l16) << 6) + ks * 32 + quad * 8);

    #pragma unroll
    for (int tm = 0; tm < 4; ++tm) {
        int row = base + tm * 16 + l16;
        int s = (row < validEnd) ? pairS[row].x : 0;
        const unsigned short* fp = featB + (s << 6) + quad * 8;
        short8 a0 = *(const short8*)(fp);
        short8 a1 = *(const short8*)(fp + 32);
        floatx4 cc[4];
        #pragma unroll
        for (int tn = 0; tn < 4; ++tn) {
            floatx4 c = {0.f, 0.f, 0.f, 0.f};
            c = __builtin_amdgcn_mfma_f32_16x16x32_bf16(a0, bfr[tn][0], c, 0, 0, 0);
            c = __builtin_amdgcn_mfma_f32_16x16x32_bf16(a1, bfr[tn][1], c, 0, 0, 0);
            cc[tn] = c;
        }
        int pos0 = base + tm * 16 + quad * 4;
        #pragma unroll
        for (int j = 0; j < 4; ++j) {
            if (pos0 + j < validEnd) {
                int dn = pairS[pos0 + j].y;
                float* op = out + (dn << 6) + l16;
                #pragma unroll
                for (int tn = 0; tn < 4; ++tn)
                    atomicAdd(op + tn * 16, cc[tn][j]);
            }
        }
    }
}

extern "C" void kernel_launch(void* const* d_in, const int* in_sizes, int n_in,
                              void* d_out, int out_size, void* d_ws, size_t ws_size,
                              hipStream_t stream) {
    const float* feat = (const float*)d_in[0];
    const float* W    = (const float*)d_in[1];
    const int* src    = (const int*)d_in[2];
    const int* dst    = (const int*)d_in[3];
    const int* et     = (const int*)d_in[4];
    float* out = (float*)d_out;
    char* ws = (char*)d_ws;

    unsigned short* featB = (unsigned short*)(ws);
    unsigned short* Wt    = (unsigned short*)(ws + 12800000);
    int* hist  = (int*)(ws + 12931072);
    int* bbase = (int*)(ws + 12963840);
    int* Pve   = (int*)(ws + 12996608);
    int* dhist = (int*)(ws + 12996864);
    int* dbase = (int*)(ws + 13396992);
    int* csum  = (int*)(ws + 13797120);
    unsigned short* rank = (unsigned short*)(ws + 13797632);
    int2* pairS = (int2*)(ws + 15797632);
    unsigned short* msgE = (unsigned short*)(ws + 23805824);

    const int usePhases = (ws_size >= WS_NEED) ? 1 : 0;

    hipMemsetAsync(dhist, 0, NDN * sizeof(int), stream);
    k_setup<<<SETUP_BLKS, 256, 0, stream>>>(feat, W, et, dst, featB, Wt, hist, dhist, rank);
    k_scan<<<1, 1024, 0, stream>>>(hist, bbase, Pve);

    if (usePhases) {
        k_dscanA<<<NCHUNK, DCH, 0, stream>>>(dhist, dbase, csum);
        k_dscanB<<<NCHUNK, DCH, 0, stream>>>(dbase, csum);
        k_scatter<<<NB, 256, 0, stream>>>(et, src, dst, bbase, dbase, rank, pairS, 1);
        k_computeA<<<(MAXTILES + 3) / 4, 256, 0, stream>>>(featB, Wt, pairS, Pve, msgE);
        k_reduce<<<(NDN + 3) / 4, 256, 0, stream>>>(msgE, dbase, out);
    } else {
        hipMemsetAsync(d_out, 0, (size_t)out_size * sizeof(float), stream);
        k_scatter<<<NB, 256, 0, stream>>>(et, src, dst, bbase, dbase, rank, pairS, 0);
        k_compute<<<(MAXTILES + 3) / 4, 256, 0, stream>>>(featB, Wt, pairS, Pve, out);
    }
}